// Round 20
// baseline (342.493 us; speedup 1.0000x reference)
//
#include <hip/hip_runtime.h>
#include <hip/hip_bf16.h>
#include <math.h>

typedef unsigned short u16;
typedef __attribute__((ext_vector_type(4))) float f32x4;
typedef __attribute__((ext_vector_type(8))) short bf16x8;

#define GLD16(gptr, lptr) __builtin_amdgcn_global_load_lds( \
    (const __attribute__((address_space(1))) void*)(gptr),  \
    (__attribute__((address_space(3))) void*)(lptr), 16, 0, 0)

__device__ __forceinline__ float bf2f(u16 u) {
  union { unsigned int i; float f; } c; c.i = ((unsigned int)u) << 16; return c.f;
}
__device__ __forceinline__ u16 f2bf(float f) {
  union { float f; unsigned int i; } c; c.f = f;
  unsigned int r = c.i + 0x7fffu + ((c.i >> 16) & 1u);
  return (u16)(r >> 16);
}

// ---------------- fp32 -> bf16 elementwise (float4 vectorized) ----------------
__global__ __launch_bounds__(256) void f32_to_bf16(const float* __restrict__ in,
                                                   u16* __restrict__ out, int n4) {
  int i = blockIdx.x * 256 + threadIdx.x;
  if (i >= n4) return;
  float4 v = reinterpret_cast<const float4*>(in)[i];
  ushort4 o;
  o.x = f2bf(v.x); o.y = f2bf(v.y); o.z = f2bf(v.z); o.w = f2bf(v.w);
  reinterpret_cast<ushort4*>(out)[i] = o;
}

// ---------------- W[K][N] fp32 -> Wt[N][K] bf16 (tiled transpose) ----------------
__global__ __launch_bounds__(256) void transpose_convert(const float* __restrict__ W,
                                                         u16* __restrict__ Wt,
                                                         int K, int N) {
  __shared__ float tile[32][33];
  const int n0 = blockIdx.x * 32, k0 = blockIdx.y * 32;
  const int tx = threadIdx.x & 31, ty = threadIdx.x >> 5;
#pragma unroll
  for (int r = 0; r < 32; r += 8)
    tile[ty + r][tx] = W[(size_t)(k0 + ty + r) * N + (n0 + tx)];
  __syncthreads();
#pragma unroll
  for (int r = 0; r < 32; r += 8)
    Wt[(size_t)(n0 + ty + r) * K + (k0 + tx)] = f2bf(tile[tx][ty + r]);
}

// ------- V cols of QKV[2048][6144] -> Vt[8][128][2048] bf16 (d-major) -------
__global__ __launch_bounds__(256) void transpose_v(const u16* __restrict__ Vsrc,
                                                   u16* __restrict__ Vt) {
  __shared__ u16 tile[32][33];
  const int t0 = blockIdx.x * 32, d0 = blockIdx.y * 32, hkv = blockIdx.z;
  const int tx = threadIdx.x & 31, ty = threadIdx.x >> 5;
#pragma unroll
  for (int r = 0; r < 32; r += 8)
    tile[ty + r][tx] = Vsrc[(size_t)(t0 + ty + r) * 6144 + hkv * 128 + d0 + tx];
  __syncthreads();
#pragma unroll
  for (int r = 0; r < 32; r += 8)
    Vt[((size_t)hkv * 128 + d0 + ty + r) * 2048 + t0 + tx] = tile[tx][ty + r];
}

// ---------------- RoPE cos/sin table: tab[t][d] for t<2048, d<64 ----------------
__global__ __launch_bounds__(256) void rope_table(float2* __restrict__ tab,
                                                  const int* __restrict__ pos_ptr) {
  int idx = blockIdx.x * 256 + threadIdx.x;  // 131072
  int d = idx & 63, t = idx >> 6;
  int pos = *pos_ptr;
  float inv = exp2f(-(float)d * (0.015625f * 18.931568569324174f));
  float ang = (float)(pos + t) * inv;
  tab[idx] = make_float2(cosf(ang), sinf(ang));
}

// ---------------- RoPE apply in-place on bf16 [T][stride] ----------------
__global__ __launch_bounds__(256) void rope_apply(u16* __restrict__ X, int nheads,
                                                  int stride,
                                                  const float2* __restrict__ tab) {
  int idx = blockIdx.x * 256 + threadIdx.x;
  int total = 2048 * nheads * 64;
  if (idx >= total) return;
  int d = idx & 63;
  int h = (idx >> 6) % nheads;
  int t = idx / (64 * nheads);
  float2 cs = tab[t * 64 + d];
  size_t base = (size_t)t * stride + h * 128 + d;
  float x1 = bf2f(X[base]);
  float x2 = bf2f(X[base + 64]);
  X[base]      = f2bf(x1 * cs.x - x2 * cs.y);
  X[base + 64] = f2bf(x2 * cs.x + x1 * cs.y);
}

// ---- 128xBN double-buffered bf16 GEMM, BK=64, 2 blocks/CU co-resident ----
// Same proven 2-phase schedule (stage(t+1) before compute(t), one
// __syncthreads/tile) at HALF the tile: acc[4][NF] fits the 128-VGPR cap of
// 4 waves/SIMD, LDS (128+BN)*64*2*2 <= 80 KB -> TWO blocks per CU. One
// block's barrier/vmcnt drain overlaps the partner's MFMA (m114 mechanism,
// the same fix that took attn 213->~95 in R13->R14).
// QKV: BN=192, grid 32x16 = 512 blocks (2/CU, perfect fill).
// Wo:  BN=128, grid 32x16 = 512 blocks, direct fp32 out (split-K + reduce gone).
// Swizzle: chunk ^ (row&7) (0-conflict proven); N-major XCD mapping.
template <int BN, int OUT_BF16>
__global__ __launch_bounds__(512, 4) void gemm_2cu(const u16* __restrict__ A,
                                                   const u16* __restrict__ Bt,
                                                   void* __restrict__ C,
                                                   int M, int N, int K) {
  constexpr int NF = BN / 64;       // B frags per wave per k-step (3 or 2)
  constexpr int WCOL = BN / 4;      // per-wave n width (48 or 32)
  constexpr int LB = BN / 64;       // B stage loads per thread (3 or 2)
  __shared__ alignas(16) u16 As[2][128 * 64];
  __shared__ alignas(16) u16 Bs[2][BN * 64];
  const int tid = threadIdx.x;
  const int lane = tid & 63, wid = tid >> 6;
  const int l15 = lane & 15, lg = lane >> 4;
  const int wm = wid >> 2, wn = wid & 3;   // 2m x 4n wave grid
  const int wvb = tid & ~63;

  // N-major XCD swizzle: each XCD owns gx/8 n-cols (B panel L2-resident)
  const int gy = gridDim.y;
  const int id0 = blockIdx.y * gridDim.x + blockIdx.x;
  const int xcd = id0 & 7;
  const int l = id0 >> 3;
  const int m0 = (l % gy) * 128;
  const int n0 = (xcd * (gridDim.x >> 3) + l / gy) * BN;

  f32x4 acc[4][NF];
#pragma unroll
  for (int i = 0; i < 4; ++i)
#pragma unroll
    for (int j = 0; j < NF; ++j) {
      f32x4 zz = {0.f, 0.f, 0.f, 0.f};
      acc[i][j] = zz;
    }

#define STAGE(s_, b_)                                                           \
  do {                                                                          \
    _Pragma("unroll")                                                           \
    for (int p = 0; p < 2; ++p) {                                               \
      const int slot = p * 512 + tid;                                           \
      const int row = slot >> 3, ch = slot & 7;                                 \
      const int col = (ch ^ (row & 7)) * 8;                                     \
      GLD16(A + (size_t)(m0 + row) * K + (s_) * 64 + col,                       \
            &As[b_][(p * 512 + wvb) * 8]);                                      \
    }                                                                           \
    _Pragma("unroll")                                                           \
    for (int p = 0; p < LB; ++p) {                                              \
      const int slot = p * 512 + tid;                                           \
      const int row = slot >> 3, ch = slot & 7;                                 \
      const int col = (ch ^ (row & 7)) * 8;                                     \
      GLD16(Bt + (size_t)(n0 + row) * K + (s_) * 64 + col,                      \
            &Bs[b_][(p * 512 + wvb) * 8]);                                      \
    }                                                                           \
  } while (0)

  STAGE(0, 0);
  __syncthreads();
  int cur = 0;

  const int nt = K >> 6;
  for (int t = 0; t < nt; ++t) {
    if (t + 1 < nt) STAGE(t + 1, cur ^ 1);
#pragma unroll
    for (int g = 0; g < 2; ++g) {
      bf16x8 af[4], bfr[NF];
#pragma unroll
      for (int i = 0; i < 4; ++i) {
        const int row = wm * 64 + i * 16 + l15;
        const int ch = (g * 4 + lg) ^ (row & 7);
        af[i] = *reinterpret_cast<const bf16x8*>(&As[cur][row * 64 + ch * 8]);
      }
#pragma unroll
      for (int j = 0; j < NF; ++j) {
        const int row = wn * WCOL + j * 16 + l15;
        const int ch = (g * 4 + lg) ^ (row & 7);
        bfr[j] = *reinterpret_cast<const bf16x8*>(&Bs[cur][row * 64 + ch * 8]);
      }
      __builtin_amdgcn_s_setprio(1);
#pragma unroll
      for (int i = 0; i < 4; ++i)
#pragma unroll
        for (int j = 0; j < NF; ++j)
          acc[i][j] = __builtin_amdgcn_mfma_f32_16x16x32_bf16(af[i], bfr[j], acc[i][j], 0, 0, 0);
      __builtin_amdgcn_s_setprio(0);
    }
    __syncthreads();
    cur ^= 1;
  }
#undef STAGE

#pragma unroll
  for (int i = 0; i < 4; ++i)
#pragma unroll
    for (int j = 0; j < NF; ++j)
#pragma unroll
      for (int r = 0; r < 4; ++r) {
        const int row = m0 + wm * 64 + i * 16 + lg * 4 + r;
        const int col = n0 + wn * WCOL + j * 16 + l15;
        const float v = acc[i][j][r];
        if (OUT_BF16) ((u16*)C)[(size_t)row * N + col] = f2bf(v);
        else          ((float*)C)[(size_t)row * N + col] = v;
      }
}

// ---------------- GQA causal flash attention (R17-proven version) ----------------
// grid (8, 32), 512 threads = 8 waves, exactly 34 KV-tiles/block (balanced),
// 256 blocks = 1/CU, 2 waves/SIMD.
__global__ __launch_bounds__(512) void attn_kernel(const u16* __restrict__ Q,
                                                   const u16* __restrict__ K,
                                                   const u16* __restrict__ Vt,
                                                   u16* __restrict__ O,
                                                   const int* __restrict__ pos_ptr) {
  const int pos = *pos_ptr;
  const int h = blockIdx.y;
  const int hkv = h >> 2;
  const int tid = threadIdx.x;
  const int w = tid >> 6, lane = tid & 63;
  const int l15 = lane & 15, lg = lane >> 4;

  __shared__ alignas(16) u16 Ks[2][64 * 128];  // K tile [64][128], swizzled
  __shared__ alignas(16) u16 Vs[2][128 * 64];  // V^T tile [128][64], swizzled
  __shared__ alignas(16) u16 Pl[8][16][72];    // per-wave P staging

  const u16* Kh = K + hkv * 128;                 // row stride 6144
  const u16* Vh = Vt + (size_t)hkv * 128 * 2048; // row stride 2048

  const float C = 0.12752961957823275f;  // (1/sqrt(128)) * log2(e)
  const float THR = 62.0f;               // raw defer-max threshold
  const int wvb = tid & ~63;

#define STAGE_TILE(st_, b_)                                                        \
  do {                                                                             \
    const int s0_ = (st_) * 64;                                                    \
    _Pragma("unroll")                                                              \
    for (int p = 0; p < 2; ++p) {                                                  \
      const int idx = p * 512 + tid;                                               \
      const int kr = idx >> 4, kc = (idx & 15) ^ (kr & 7);                         \
      GLD16(Kh + (size_t)(s0_ + kr) * 6144 + kc * 8, &Ks[b_][(p * 512 + wvb) * 8]);\
      const int vr = idx >> 3, vc = (idx & 7) ^ (vr & 7);                          \
      GLD16(Vh + (size_t)vr * 2048 + s0_ + vc * 8, &Vs[b_][(p * 512 + wvb) * 8]);  \
    }                                                                              \
  } while (0)

  for (int pass = 0; pass < 2; ++pass) {
    const int qb = (pass == 0) ? (8 + (int)blockIdx.x) : (7 - (int)blockIdx.x);
    const int qt0 = qb * 128;
    const int nst = 2 * qb + 2;
    const int frag_base = qt0 + w * 16;

    bf16x8 qa[4];
#pragma unroll
    for (int kk = 0; kk < 4; ++kk)
      qa[kk] = *reinterpret_cast<const bf16x8*>(
          Q + (size_t)(frag_base + l15) * 6144 + h * 128 + kk * 32 + lg * 8);

    f32x4 acc[8];
#pragma unroll
    for (int i = 0; i < 8; ++i) { f32x4 z = {0.f, 0.f, 0.f, 0.f}; acc[i] = z; }
    float mrun[4], lpart[4];
#pragma unroll
    for (int r = 0; r < 4; ++r) {
      mrun[r] = (pos > 0) ? 0.0f : -INFINITY;  // zero-key prefix logit = 0 (raw)
      lpart[r] = 0.0f;
    }

    STAGE_TILE(0, 0);
    __syncthreads();
    int cur = 0;

    for (int st = 0; st < nst; ++st) {
      if (st + 1 < nst) STAGE_TILE(st + 1, cur ^ 1);
      const int s0 = st * 64;

      // ---- QK^T (raw logits) ----
      float pv[4][4];
      __builtin_amdgcn_s_setprio(1);
#pragma unroll
      for (int sub = 0; sub < 4; ++sub) {
        f32x4 s4 = {0.f, 0.f, 0.f, 0.f};
        const int row = sub * 16 + l15;
#pragma unroll
        for (int kk = 0; kk < 4; ++kk) {
          const int chunk = (kk * 4 + lg) ^ (row & 7);
          bf16x8 kf = *reinterpret_cast<const bf16x8*>(&Ks[cur][row * 128 + chunk * 8]);
          s4 = __builtin_amdgcn_mfma_f32_16x16x32_bf16(qa[kk], kf, s4, 0, 0, 0);
        }
#pragma unroll
        for (int r = 0; r < 4; ++r) pv[sub][r] = s4[r];
      }
      __builtin_amdgcn_s_setprio(0);

      // ---- causal mask (diagonal tiles only) ----
      if (s0 + 64 > frag_base) {
#pragma unroll
        for (int r = 0; r < 4; ++r) {
          const int qrow = frag_base + lg * 4 + r;
#pragma unroll
          for (int sub = 0; sub < 4; ++sub) {
            const int scol = s0 + sub * 16 + l15;
            pv[sub][r] = (scol <= qrow) ? pv[sub][r] : -INFINITY;
          }
        }
      }

      // ---- defer-max ----
      float lmax[4];
#pragma unroll
      for (int r = 0; r < 4; ++r)
        lmax[r] = fmaxf(fmaxf(pv[0][r], pv[1][r]), fmaxf(pv[2][r], pv[3][r]));
      float dml = fmaxf(fmaxf(lmax[0] - mrun[0], lmax[1] - mrun[1]),
                        fmaxf(lmax[2] - mrun[2], lmax[3] - mrun[3]));
      if (!__all(dml <= THR)) {
        float sfr[4];
#pragma unroll
        for (int r = 0; r < 4; ++r) {
          float mx = lmax[r];
#pragma unroll
          for (int off = 1; off < 16; off <<= 1) mx = fmaxf(mx, __shfl_xor(mx, off));
          const float mnew = fmaxf(mrun[r], mx);
          sfr[r] = exp2f((mrun[r] - mnew) * C);
          mrun[r] = mnew;
          lpart[r] *= sfr[r];
        }
#pragma unroll
        for (int dc = 0; dc < 8; ++dc)
#pragma unroll
          for (int r = 0; r < 4; ++r) acc[dc][r] *= sfr[r];
      }

      // ---- P = exp2(fma(s, C, -m*C)), per-lane partial row-sums ----
#pragma unroll
      for (int r = 0; r < 4; ++r) {
        const float nmC = -mrun[r] * C;
        float ps = 0.0f;
#pragma unroll
        for (int sub = 0; sub < 4; ++sub) {
          const float p = exp2f(fmaf(pv[sub][r], C, nmC));
          pv[sub][r] = p;
          ps += p;
        }
        lpart[r] += ps;
      }

      // ---- P -> per-wave LDS (wave-local, no barrier) ----
#pragma unroll
      for (int sub = 0; sub < 4; ++sub)
#pragma unroll
        for (int r = 0; r < 4; ++r)
          Pl[w][lg * 4 + r][sub * 16 + l15] = f2bf(pv[sub][r]);

      // ---- PV ----
      __builtin_amdgcn_s_setprio(1);
#pragma unroll
      for (int ks = 0; ks < 2; ++ks) {
        bf16x8 pf = *reinterpret_cast<const bf16x8*>(&Pl[w][l15][ks * 32 + lg * 8]);
#pragma unroll
        for (int dc = 0; dc < 8; ++dc) {
          const int row = dc * 16 + l15;
          const int chunk = (ks * 4 + lg) ^ (row & 7);
          bf16x8 vf = *reinterpret_cast<const bf16x8*>(&Vs[cur][row * 64 + chunk * 8]);
          acc[dc] = __builtin_amdgcn_mfma_f32_16x16x32_bf16(pf, vf, acc[dc], 0, 0, 0);
        }
      }
      __builtin_amdgcn_s_setprio(0);

      __syncthreads();
      cur ^= 1;
    }

    // ---- epilogue ----
#pragma unroll
    for (int r = 0; r < 4; ++r) {
      float l = lpart[r];
#pragma unroll
      for (int off = 1; off < 16; off <<= 1) l += __shfl_xor(l, off);
      if (pos > 0) l += (float)pos * exp2f(-mrun[r] * C);
      const float linv = 1.0f / l;
      const int qrow = frag_base + lg * 4 + r;
#pragma unroll
      for (int dc = 0; dc < 8; ++dc)
        O[(size_t)qrow * 4096 + h * 128 + dc * 16 + l15] = f2bf(acc[dc][r] * linv);
    }
  }
#undef STAGE_TILE
}

extern "C" void kernel_launch(void* const* d_in, const int* in_sizes, int n_in,
                              void* d_out, int out_size, void* d_ws, size_t ws_size,
                              hipStream_t stream) {
  const float* hs = (const float*)d_in[0];
  const float* Wq = (const float*)d_in[1];
  const float* Wk = (const float*)d_in[2];
  const float* Wv = (const float*)d_in[3];
  const float* Wo = (const float*)d_in[4];
  const int* pos  = (const int*)d_in[5];

  char* ws = (char*)d_ws;
  // layout (88 MB total):
  u16* hs_bf = (u16*)(ws + 0);            // [2048][4096] bf16 (16 MB)
  u16* WT    = (u16*)(ws + 16777216ULL);  // [6144][4096] bf16 (48 MB): Wq|Wk|Wv rows
  u16* QKVb  = (u16*)(ws + 67108864ULL);  // [2048][6144] bf16 (24 MB)
  // aliases of dead regions:
  u16* attnO = hs_bf;                          // [2048][4096], hs_bf dead post-QKV
  u16* WoT   = WT;                             // [4096][4096], WqT rows dead
  u16* Vtg   = (u16*)(ws + 50331648ULL);       // [8][128][2048] (4 MB), WkT rows dead
  float2* tabF = (float2*)(ws + 54525952ULL);  // [2048][64] (1 MB), WvT rows dead

  f32_to_bf16<<<8192, 256, 0, stream>>>(hs, hs_bf, 2097152);
  transpose_convert<<<dim3(128, 128), 256, 0, stream>>>(Wq, WT, 4096, 4096);
  transpose_convert<<<dim3(32, 128), 256, 0, stream>>>(Wk, WT + (size_t)4096 * 4096, 4096, 1024);
  transpose_convert<<<dim3(32, 128), 256, 0, stream>>>(Wv, WT + (size_t)5120 * 4096, 4096, 1024);

  // fused QKV projection, BM=128/BN=192: 512 blocks = 2 blocks/CU
  gemm_2cu<192, 1><<<dim3(32, 16), 512, 0, stream>>>(hs_bf, WT, QKVb, 2048, 6144, 4096);

  // Wo transpose AFTER QKV GEMM (WoT overwrites dead WqT rows)
  transpose_convert<<<dim3(128, 128), 256, 0, stream>>>(Wo, WoT, 4096, 4096);

  rope_table<<<512, 256, 0, stream>>>(tabF, pos);
  rope_apply<<<16384, 256, 0, stream>>>(QKVb, 32, 6144, tabF);        // Q cols
  rope_apply<<<4096, 256, 0, stream>>>(QKVb + 4096, 8, 6144, tabF);   // K cols

  // V cols -> Vt[hkv][d][t]
  transpose_v<<<dim3(64, 4, 8), 256, 0, stream>>>(QKVb + 5120, Vtg);

  attn_kernel<<<dim3(8, 32), 512, 0, stream>>>(QKVb, QKVb + 4096, Vtg, attnO, pos);

  // output projection, BM=128/BN=128: 512 blocks = 2 blocks/CU, direct fp32 out
  gemm_2cu<128, 0><<<dim3(32, 16), 512, 0, stream>>>(attnO, WoT, d_out, 2048, 4096, 4096);
}

// Round 21
// 341.955 us; speedup vs baseline: 1.0016x; 1.0016x over previous
//
#include <hip/hip_runtime.h>
#include <hip/hip_bf16.h>
#include <math.h>

typedef unsigned short u16;
typedef __attribute__((ext_vector_type(4))) float f32x4;
typedef __attribute__((ext_vector_type(8))) short bf16x8;

#define GLD16(gptr, lptr) __builtin_amdgcn_global_load_lds( \
    (const __attribute__((address_space(1))) void*)(gptr),  \
    (__attribute__((address_space(3))) void*)(lptr), 16, 0, 0)

__device__ __forceinline__ float bf2f(u16 u) {
  union { unsigned int i; float f; } c; c.i = ((unsigned int)u) << 16; return c.f;
}
__device__ __forceinline__ u16 f2bf(float f) {
  union { float f; unsigned int i; } c; c.f = f;
  unsigned int r = c.i + 0x7fffu + ((c.i >> 16) & 1u);
  return (u16)(r >> 16);
}

// ---------------- fp32 -> bf16 elementwise (float4 vectorized) ----------------
__global__ __launch_bounds__(256) void f32_to_bf16(const float* __restrict__ in,
                                                   u16* __restrict__ out, int n4) {
  int i = blockIdx.x * 256 + threadIdx.x;
  if (i >= n4) return;
  float4 v = reinterpret_cast<const float4*>(in)[i];
  ushort4 o;
  o.x = f2bf(v.x); o.y = f2bf(v.y); o.z = f2bf(v.z); o.w = f2bf(v.w);
  reinterpret_cast<ushort4*>(out)[i] = o;
}

// ---- combined Wq|Wk|Wv [4096][N] fp32 -> WT[6144][4096] bf16 transpose ----
// grid (192,128): bx<128 -> Wq (N=4096); bx<160 -> Wk; else Wv (N=1024 each).
__global__ __launch_bounds__(256) void transpose_qkv_w(const float* __restrict__ Wq,
                                                       const float* __restrict__ Wk,
                                                       const float* __restrict__ Wv,
                                                       u16* __restrict__ WT) {
  __shared__ float tile[32][33];
  const int bx = blockIdx.x, k0 = blockIdx.y * 32;
  const float* W; int n0, N; size_t outbase;
  if (bx < 128)      { W = Wq; n0 = bx * 32;          N = 4096; outbase = 0; }
  else if (bx < 160) { W = Wk; n0 = (bx - 128) * 32;  N = 1024; outbase = (size_t)4096 * 4096; }
  else               { W = Wv; n0 = (bx - 160) * 32;  N = 1024; outbase = (size_t)5120 * 4096; }
  const int tx = threadIdx.x & 31, ty = threadIdx.x >> 5;
#pragma unroll
  for (int r = 0; r < 32; r += 8)
    tile[ty + r][tx] = W[(size_t)(k0 + ty + r) * N + (n0 + tx)];
  __syncthreads();
#pragma unroll
  for (int r = 0; r < 32; r += 8)
    WT[outbase + (size_t)(n0 + ty + r) * 4096 + (k0 + tx)] = f2bf(tile[tx][ty + r]);
}

// ---------------- W[K][N] fp32 -> Wt[N][K] bf16 (tiled transpose) ----------------
__global__ __launch_bounds__(256) void transpose_convert(const float* __restrict__ W,
                                                         u16* __restrict__ Wt,
                                                         int K, int N) {
  __shared__ float tile[32][33];
  const int n0 = blockIdx.x * 32, k0 = blockIdx.y * 32;
  const int tx = threadIdx.x & 31, ty = threadIdx.x >> 5;
#pragma unroll
  for (int r = 0; r < 32; r += 8)
    tile[ty + r][tx] = W[(size_t)(k0 + ty + r) * N + (n0 + tx)];
  __syncthreads();
#pragma unroll
  for (int r = 0; r < 32; r += 8)
    Wt[(size_t)(n0 + ty + r) * K + (k0 + tx)] = f2bf(tile[tx][ty + r]);
}

// ------- V cols of QKV[2048][6144] -> Vt[8][128][2048] bf16 (d-major) -------
__global__ __launch_bounds__(256) void transpose_v(const u16* __restrict__ Vsrc,
                                                   u16* __restrict__ Vt) {
  __shared__ u16 tile[32][33];
  const int t0 = blockIdx.x * 32, d0 = blockIdx.y * 32, hkv = blockIdx.z;
  const int tx = threadIdx.x & 31, ty = threadIdx.x >> 5;
#pragma unroll
  for (int r = 0; r < 32; r += 8)
    tile[ty + r][tx] = Vsrc[(size_t)(t0 + ty + r) * 6144 + hkv * 128 + d0 + tx];
  __syncthreads();
#pragma unroll
  for (int r = 0; r < 32; r += 8)
    Vt[((size_t)hkv * 128 + d0 + ty + r) * 2048 + t0 + tx] = tile[tx][ty + r];
}

// ---------------- RoPE cos/sin table: tab[t][d] for t<2048, d<64 ----------------
__global__ __launch_bounds__(256) void rope_table(float2* __restrict__ tab,
                                                  const int* __restrict__ pos_ptr) {
  int idx = blockIdx.x * 256 + threadIdx.x;  // 131072
  int d = idx & 63, t = idx >> 6;
  int pos = *pos_ptr;
  float inv = exp2f(-(float)d * (0.015625f * 18.931568569324174f));
  float ang = (float)(pos + t) * inv;
  tab[idx] = make_float2(cosf(ang), sinf(ang));
}

// ---- RoPE apply in-place on QKV[2048][6144]: Q heads 0-31, K heads 32-39 ----
__global__ __launch_bounds__(256) void rope_apply_qk(u16* __restrict__ QKV,
                                                     const float2* __restrict__ tab) {
  int idx = blockIdx.x * 256 + threadIdx.x;
  if (idx >= 2048 * 40 * 64) return;
  int d = idx & 63;
  int hh = (idx >> 6) % 40;
  int t = idx / (64 * 40);
  float2 cs = tab[t * 64 + d];
  const int col = (hh < 32) ? hh * 128 : 4096 + (hh - 32) * 128;
  size_t base = (size_t)t * 6144 + col + d;
  float x1 = bf2f(QKV[base]);
  float x2 = bf2f(QKV[base + 64]);
  QKV[base]      = f2bf(x1 * cs.x - x2 * cs.y);
  QKV[base + 64] = f2bf(x2 * cs.x + x1 * cs.y);
}

// ---- 128xBN double-buffered bf16 GEMM, BK=64, 2 blocks/CU (R20-proven) ----
template <int BN, int OUT_BF16>
__global__ __launch_bounds__(512, 4) void gemm_2cu(const u16* __restrict__ A,
                                                   const u16* __restrict__ Bt,
                                                   void* __restrict__ C,
                                                   int M, int N, int K) {
  constexpr int NF = BN / 64;
  constexpr int WCOL = BN / 4;
  constexpr int LB = BN / 64;
  __shared__ alignas(16) u16 As[2][128 * 64];
  __shared__ alignas(16) u16 Bs[2][BN * 64];
  const int tid = threadIdx.x;
  const int lane = tid & 63, wid = tid >> 6;
  const int l15 = lane & 15, lg = lane >> 4;
  const int wm = wid >> 2, wn = wid & 3;
  const int wvb = tid & ~63;

  const int gy = gridDim.y;
  const int id0 = blockIdx.y * gridDim.x + blockIdx.x;
  const int xcd = id0 & 7;
  const int l = id0 >> 3;
  const int m0 = (l % gy) * 128;
  const int n0 = (xcd * (gridDim.x >> 3) + l / gy) * BN;

  f32x4 acc[4][NF];
#pragma unroll
  for (int i = 0; i < 4; ++i)
#pragma unroll
    for (int j = 0; j < NF; ++j) {
      f32x4 zz = {0.f, 0.f, 0.f, 0.f};
      acc[i][j] = zz;
    }

#define STAGE(s_, b_)                                                           \
  do {                                                                          \
    _Pragma("unroll")                                                           \
    for (int p = 0; p < 2; ++p) {                                               \
      const int slot = p * 512 + tid;                                           \
      const int row = slot >> 3, ch = slot & 7;                                 \
      const int col = (ch ^ (row & 7)) * 8;                                     \
      GLD16(A + (size_t)(m0 + row) * K + (s_) * 64 + col,                       \
            &As[b_][(p * 512 + wvb) * 8]);                                      \
    }                                                                           \
    _Pragma("unroll")                                                           \
    for (int p = 0; p < LB; ++p) {                                              \
      const int slot = p * 512 + tid;                                           \
      const int row = slot >> 3, ch = slot & 7;                                 \
      const int col = (ch ^ (row & 7)) * 8;                                     \
      GLD16(Bt + (size_t)(n0 + row) * K + (s_) * 64 + col,                      \
            &Bs[b_][(p * 512 + wvb) * 8]);                                      \
    }                                                                           \
  } while (0)

  STAGE(0, 0);
  __syncthreads();
  int cur = 0;

  const int nt = K >> 6;
  for (int t = 0; t < nt; ++t) {
    if (t + 1 < nt) STAGE(t + 1, cur ^ 1);
#pragma unroll
    for (int g = 0; g < 2; ++g) {
      bf16x8 af[4], bfr[NF];
#pragma unroll
      for (int i = 0; i < 4; ++i) {
        const int row = wm * 64 + i * 16 + l15;
        const int ch = (g * 4 + lg) ^ (row & 7);
        af[i] = *reinterpret_cast<const bf16x8*>(&As[cur][row * 64 + ch * 8]);
      }
#pragma unroll
      for (int j = 0; j < NF; ++j) {
        const int row = wn * WCOL + j * 16 + l15;
        const int ch = (g * 4 + lg) ^ (row & 7);
        bfr[j] = *reinterpret_cast<const bf16x8*>(&Bs[cur][row * 64 + ch * 8]);
      }
      __builtin_amdgcn_s_setprio(1);
#pragma unroll
      for (int i = 0; i < 4; ++i)
#pragma unroll
        for (int j = 0; j < NF; ++j)
          acc[i][j] = __builtin_amdgcn_mfma_f32_16x16x32_bf16(af[i], bfr[j], acc[i][j], 0, 0, 0);
      __builtin_amdgcn_s_setprio(0);
    }
    __syncthreads();
    cur ^= 1;
  }
#undef STAGE

#pragma unroll
  for (int i = 0; i < 4; ++i)
#pragma unroll
    for (int j = 0; j < NF; ++j)
#pragma unroll
      for (int r = 0; r < 4; ++r) {
        const int row = m0 + wm * 64 + i * 16 + lg * 4 + r;
        const int col = n0 + wn * WCOL + j * 16 + l15;
        const float v = acc[i][j][r];
        if (OUT_BF16) ((u16*)C)[(size_t)row * N + col] = f2bf(v);
        else          ((float*)C)[(size_t)row * N + col] = v;
      }
}

// ---------------- GQA causal flash attention ----------------
// grid (8, 32) = 256 blocks, 512 threads = 8 waves, exactly 34 KV-tiles/block.
// XCD-resident KV: block id -> (hkv = id&7 = XCD, h-sub, q-pair) so every
// block on XCD x works kv-head x -> its K/V/Vt (~3 MB) stay in that XCD's L2
// (staging latency L2 ~200cyc instead of L3/HBM ~600-900cyc).
__global__ __launch_bounds__(512) void attn_kernel(const u16* __restrict__ Q,
                                                   const u16* __restrict__ K,
                                                   const u16* __restrict__ Vt,
                                                   u16* __restrict__ O,
                                                   const int* __restrict__ pos_ptr) {
  const int pos = *pos_ptr;
  const int id = (int)(blockIdx.y * gridDim.x + blockIdx.x);
  const int hkv = id & 7;                 // == XCD for linear round-robin dispatch
  const int h = hkv * 4 + ((id >> 3) & 3);
  const int qp = id >> 5;                 // 0..7
  const int tid = threadIdx.x;
  const int w = tid >> 6, lane = tid & 63;
  const int l15 = lane & 15, lg = lane >> 4;

  __shared__ alignas(16) u16 Ks[2][64 * 128];  // K tile [64][128], swizzled
  __shared__ alignas(16) u16 Vs[2][128 * 64];  // V^T tile [128][64], swizzled
  __shared__ alignas(16) u16 Pl[8][16][72];    // per-wave P staging

  const u16* Kh = K + hkv * 128;                 // row stride 6144
  const u16* Vh = Vt + (size_t)hkv * 128 * 2048; // row stride 2048

  const float C = 0.12752961957823275f;  // (1/sqrt(128)) * log2(e)
  const float THR = 62.0f;               // raw defer-max threshold
  const int wvb = tid & ~63;

#define STAGE_TILE(st_, b_)                                                        \
  do {                                                                             \
    const int s0_ = (st_) * 64;                                                    \
    _Pragma("unroll")                                                              \
    for (int p = 0; p < 2; ++p) {                                                  \
      const int idx = p * 512 + tid;                                               \
      const int kr = idx >> 4, kc = (idx & 15) ^ (kr & 7);                         \
      GLD16(Kh + (size_t)(s0_ + kr) * 6144 + kc * 8, &Ks[b_][(p * 512 + wvb) * 8]);\
      const int vr = idx >> 3, vc = (idx & 7) ^ (vr & 7);                          \
      GLD16(Vh + (size_t)vr * 2048 + s0_ + vc * 8, &Vs[b_][(p * 512 + wvb) * 8]);  \
    }                                                                              \
  } while (0)

  for (int pass = 0; pass < 2; ++pass) {
    const int qb = (pass == 0) ? (8 + qp) : (7 - qp);
    const int qt0 = qb * 128;
    const int nst = 2 * qb + 2;
    const int frag_base = qt0 + w * 16;

    bf16x8 qa[4];
#pragma unroll
    for (int kk = 0; kk < 4; ++kk)
      qa[kk] = *reinterpret_cast<const bf16x8*>(
          Q + (size_t)(frag_base + l15) * 6144 + h * 128 + kk * 32 + lg * 8);

    f32x4 acc[8];
#pragma unroll
    for (int i = 0; i < 8; ++i) { f32x4 z = {0.f, 0.f, 0.f, 0.f}; acc[i] = z; }
    float mrun[4], lpart[4];
#pragma unroll
    for (int r = 0; r < 4; ++r) {
      mrun[r] = (pos > 0) ? 0.0f : -INFINITY;  // zero-key prefix logit = 0 (raw)
      lpart[r] = 0.0f;
    }

    STAGE_TILE(0, 0);
    __syncthreads();
    int cur = 0;

    for (int st = 0; st < nst; ++st) {
      if (st + 1 < nst) STAGE_TILE(st + 1, cur ^ 1);
      const int s0 = st * 64;

      // ---- QK^T (raw logits) ----
      float pv[4][4];
      __builtin_amdgcn_s_setprio(1);
#pragma unroll
      for (int sub = 0; sub < 4; ++sub) {
        f32x4 s4 = {0.f, 0.f, 0.f, 0.f};
        const int row = sub * 16 + l15;
#pragma unroll
        for (int kk = 0; kk < 4; ++kk) {
          const int chunk = (kk * 4 + lg) ^ (row & 7);
          bf16x8 kf = *reinterpret_cast<const bf16x8*>(&Ks[cur][row * 128 + chunk * 8]);
          s4 = __builtin_amdgcn_mfma_f32_16x16x32_bf16(qa[kk], kf, s4, 0, 0, 0);
        }
#pragma unroll
        for (int r = 0; r < 4; ++r) pv[sub][r] = s4[r];
      }
      __builtin_amdgcn_s_setprio(0);

      // ---- causal mask (diagonal tiles only) ----
      if (s0 + 64 > frag_base) {
#pragma unroll
        for (int r = 0; r < 4; ++r) {
          const int qrow = frag_base + lg * 4 + r;
#pragma unroll
          for (int sub = 0; sub < 4; ++sub) {
            const int scol = s0 + sub * 16 + l15;
            pv[sub][r] = (scol <= qrow) ? pv[sub][r] : -INFINITY;
          }
        }
      }

      // ---- defer-max ----
      float lmax[4];
#pragma unroll
      for (int r = 0; r < 4; ++r)
        lmax[r] = fmaxf(fmaxf(pv[0][r], pv[1][r]), fmaxf(pv[2][r], pv[3][r]));
      float dml = fmaxf(fmaxf(lmax[0] - mrun[0], lmax[1] - mrun[1]),
                        fmaxf(lmax[2] - mrun[2], lmax[3] - mrun[3]));
      if (!__all(dml <= THR)) {
        float sfr[4];
#pragma unroll
        for (int r = 0; r < 4; ++r) {
          float mx = lmax[r];
#pragma unroll
          for (int off = 1; off < 16; off <<= 1) mx = fmaxf(mx, __shfl_xor(mx, off));
          const float mnew = fmaxf(mrun[r], mx);
          sfr[r] = exp2f((mrun[r] - mnew) * C);
          mrun[r] = mnew;
          lpart[r] *= sfr[r];
        }
#pragma unroll
        for (int dc = 0; dc < 8; ++dc)
#pragma unroll
          for (int r = 0; r < 4; ++r) acc[dc][r] *= sfr[r];
      }

      // ---- P = exp2(fma(s, C, -m*C)), per-lane partial row-sums ----
#pragma unroll
      for (int r = 0; r < 4; ++r) {
        const float nmC = -mrun[r] * C;
        float ps = 0.0f;
#pragma unroll
        for (int sub = 0; sub < 4; ++sub) {
          const float p = exp2f(fmaf(pv[sub][r], C, nmC));
          pv[sub][r] = p;
          ps += p;
        }
        lpart[r] += ps;
      }

      // ---- P -> per-wave LDS (wave-local, no barrier) ----
#pragma unroll
      for (int sub = 0; sub < 4; ++sub)
#pragma unroll
        for (int r = 0; r < 4; ++r)
          Pl[w][lg * 4 + r][sub * 16 + l15] = f2bf(pv[sub][r]);

      // ---- PV ----
      __builtin_amdgcn_s_setprio(1);
#pragma unroll
      for (int ks = 0; ks < 2; ++ks) {
        bf16x8 pf = *reinterpret_cast<const bf16x8*>(&Pl[w][l15][ks * 32 + lg * 8]);
#pragma unroll
        for (int dc = 0; dc < 8; ++dc) {
          const int row = dc * 16 + l15;
          const int chunk = (ks * 4 + lg) ^ (row & 7);
          bf16x8 vf = *reinterpret_cast<const bf16x8*>(&Vs[cur][row * 64 + chunk * 8]);
          acc[dc] = __builtin_amdgcn_mfma_f32_16x16x32_bf16(pf, vf, acc[dc], 0, 0, 0);
        }
      }
      __builtin_amdgcn_s_setprio(0);

      __syncthreads();
      cur ^= 1;
    }

    // ---- epilogue ----
#pragma unroll
    for (int r = 0; r < 4; ++r) {
      float l = lpart[r];
#pragma unroll
      for (int off = 1; off < 16; off <<= 1) l += __shfl_xor(l, off);
      if (pos > 0) l += (float)pos * exp2f(-mrun[r] * C);
      const float linv = 1.0f / l;
      const int qrow = frag_base + lg * 4 + r;
#pragma unroll
      for (int dc = 0; dc < 8; ++dc)
        O[(size_t)qrow * 4096 + h * 128 + dc * 16 + l15] = f2bf(acc[dc][r] * linv);
    }
  }
#undef STAGE_TILE
}

extern "C" void kernel_launch(void* const* d_in, const int* in_sizes, int n_in,
                              void* d_out, int out_size, void* d_ws, size_t ws_size,
                              hipStream_t stream) {
  const float* hs = (const float*)d_in[0];
  const float* Wq = (const float*)d_in[1];
  const float* Wk = (const float*)d_in[2];
  const float* Wv = (const float*)d_in[3];
  const float* Wo = (const float*)d_in[4];
  const int* pos  = (const int*)d_in[5];

  char* ws = (char*)d_ws;
  // layout (88 MB total):
  u16* hs_bf = (u16*)(ws + 0);            // [2048][4096] bf16 (16 MB)
  u16* WT    = (u16*)(ws + 16777216ULL);  // [6144][4096] bf16 (48 MB): Wq|Wk|Wv rows
  u16* QKVb  = (u16*)(ws + 67108864ULL);  // [2048][6144] bf16 (24 MB)
  // aliases of dead regions:
  u16* attnO = hs_bf;                          // [2048][4096], hs_bf dead post-QKV
  u16* WoT   = WT;                             // [4096][4096], WqT rows dead
  u16* Vtg   = (u16*)(ws + 50331648ULL);       // [8][128][2048] (4 MB), WkT rows dead
  float2* tabF = (float2*)(ws + 54525952ULL);  // [2048][64] (1 MB), WvT rows dead

  f32_to_bf16<<<8192, 256, 0, stream>>>(hs, hs_bf, 2097152);
  transpose_qkv_w<<<dim3(192, 128), 256, 0, stream>>>(Wq, Wk, Wv, WT);

  // fused QKV projection, BM=128/BN=192: 512 blocks = 2 blocks/CU
  gemm_2cu<192, 1><<<dim3(32, 16), 512, 0, stream>>>(hs_bf, WT, QKVb, 2048, 6144, 4096);

  // Wo transpose AFTER QKV GEMM (WoT overwrites dead WqT rows)
  transpose_convert<<<dim3(128, 128), 256, 0, stream>>>(Wo, WoT, 4096, 4096);

  rope_table<<<512, 256, 0, stream>>>(tabF, pos);
  rope_apply_qk<<<20480, 256, 0, stream>>>(QKVb, tabF);

  // V cols -> Vt[hkv][d][t]
  transpose_v<<<dim3(64, 4, 8), 256, 0, stream>>>(QKVb + 5120, Vtg);

  attn_kernel<<<dim3(8, 32), 512, 0, stream>>>(QKVb, QKVb + 4096, Vtg, attnO, pos);

  // output projection, BM=128/BN=128: 512 blocks = 2 blocks/CU, direct fp32 out
  gemm_2cu<128, 0><<<dim3(32, 16), 512, 0, stream>>>(attnO, WoT, d_out, 2048, 4096, 4096);
}

// Round 22
// 331.890 us; speedup vs baseline: 1.0319x; 1.0303x over previous
//
#include <hip/hip_runtime.h>
#include <hip/hip_bf16.h>
#include <math.h>

typedef unsigned short u16;
typedef __attribute__((ext_vector_type(4))) float f32x4;
typedef __attribute__((ext_vector_type(8))) short bf16x8;

#define GLD16(gptr, lptr) __builtin_amdgcn_global_load_lds( \
    (const __attribute__((address_space(1))) void*)(gptr),  \
    (__attribute__((address_space(3))) void*)(lptr), 16, 0, 0)

__device__ __forceinline__ float bf2f(u16 u) {
  union { unsigned int i; float f; } c; c.i = ((unsigned int)u) << 16; return c.f;
}
__device__ __forceinline__ u16 f2bf(float f) {
  union { float f; unsigned int i; } c; c.f = f;
  unsigned int r = c.i + 0x7fffu + ((c.i >> 16) & 1u);
  return (u16)(r >> 16);
}

// ---------------- fp32 -> bf16 elementwise (float4 vectorized) ----------------
__global__ __launch_bounds__(256) void f32_to_bf16(const float* __restrict__ in,
                                                   u16* __restrict__ out, int n4) {
  int i = blockIdx.x * 256 + threadIdx.x;
  if (i >= n4) return;
  float4 v = reinterpret_cast<const float4*>(in)[i];
  ushort4 o;
  o.x = f2bf(v.x); o.y = f2bf(v.y); o.z = f2bf(v.z); o.w = f2bf(v.w);
  reinterpret_cast<ushort4*>(out)[i] = o;
}

// ---- combined Wq|Wk|Wv [4096][N] fp32 -> WT[6144][4096] bf16 transpose ----
__global__ __launch_bounds__(256) void transpose_qkv_w(const float* __restrict__ Wq,
                                                       const float* __restrict__ Wk,
                                                       const float* __restrict__ Wv,
                                                       u16* __restrict__ WT) {
  __shared__ float tile[32][33];
  const int bx = blockIdx.x, k0 = blockIdx.y * 32;
  const float* W; int n0, N; size_t outbase;
  if (bx < 128)      { W = Wq; n0 = bx * 32;          N = 4096; outbase = 0; }
  else if (bx < 160) { W = Wk; n0 = (bx - 128) * 32;  N = 1024; outbase = (size_t)4096 * 4096; }
  else               { W = Wv; n0 = (bx - 160) * 32;  N = 1024; outbase = (size_t)5120 * 4096; }
  const int tx = threadIdx.x & 31, ty = threadIdx.x >> 5;
#pragma unroll
  for (int r = 0; r < 32; r += 8)
    tile[ty + r][tx] = W[(size_t)(k0 + ty + r) * N + (n0 + tx)];
  __syncthreads();
#pragma unroll
  for (int r = 0; r < 32; r += 8)
    WT[outbase + (size_t)(n0 + ty + r) * 4096 + (k0 + tx)] = f2bf(tile[tx][ty + r]);
}

// ---------------- W[K][N] fp32 -> Wt[N][K] bf16 (tiled transpose) ----------------
__global__ __launch_bounds__(256) void transpose_convert(const float* __restrict__ W,
                                                         u16* __restrict__ Wt,
                                                         int K, int N) {
  __shared__ float tile[32][33];
  const int n0 = blockIdx.x * 32, k0 = blockIdx.y * 32;
  const int tx = threadIdx.x & 31, ty = threadIdx.x >> 5;
#pragma unroll
  for (int r = 0; r < 32; r += 8)
    tile[ty + r][tx] = W[(size_t)(k0 + ty + r) * N + (n0 + tx)];
  __syncthreads();
#pragma unroll
  for (int r = 0; r < 32; r += 8)
    Wt[(size_t)(n0 + ty + r) * K + (k0 + tx)] = f2bf(tile[tx][ty + r]);
}

// ------- V cols of QKV[2048][6144] -> Vt[8][128][2048] bf16 (d-major) -------
__global__ __launch_bounds__(256) void transpose_v(const u16* __restrict__ Vsrc,
                                                   u16* __restrict__ Vt) {
  __shared__ u16 tile[32][33];
  const int t0 = blockIdx.x * 32, d0 = blockIdx.y * 32, hkv = blockIdx.z;
  const int tx = threadIdx.x & 31, ty = threadIdx.x >> 5;
#pragma unroll
  for (int r = 0; r < 32; r += 8)
    tile[ty + r][tx] = Vsrc[(size_t)(t0 + ty + r) * 6144 + hkv * 128 + d0 + tx];
  __syncthreads();
#pragma unroll
  for (int r = 0; r < 32; r += 8)
    Vt[((size_t)hkv * 128 + d0 + ty + r) * 2048 + t0 + tx] = tile[tx][ty + r];
}

// ---------------- RoPE cos/sin table: tab[t][d] for t<2048, d<64 ----------------
__global__ __launch_bounds__(256) void rope_table(float2* __restrict__ tab,
                                                  const int* __restrict__ pos_ptr) {
  int idx = blockIdx.x * 256 + threadIdx.x;  // 131072
  int d = idx & 63, t = idx >> 6;
  int pos = *pos_ptr;
  float inv = exp2f(-(float)d * (0.015625f * 18.931568569324174f));
  float ang = (float)(pos + t) * inv;
  tab[idx] = make_float2(cosf(ang), sinf(ang));
}

// ---- RoPE apply in-place on QKV[2048][6144]: Q heads 0-31, K heads 32-39 ----
__global__ __launch_bounds__(256) void rope_apply_qk(u16* __restrict__ QKV,
                                                     const float2* __restrict__ tab) {
  int idx = blockIdx.x * 256 + threadIdx.x;
  if (idx >= 2048 * 40 * 64) return;
  int d = idx & 63;
  int hh = (idx >> 6) % 40;
  int t = idx / (64 * 40);
  float2 cs = tab[t * 64 + d];
  const int col = (hh < 32) ? hh * 128 : 4096 + (hh - 32) * 128;
  size_t base = (size_t)t * 6144 + col + d;
  float x1 = bf2f(QKV[base]);
  float x2 = bf2f(QKV[base + 64]);
  QKV[base]      = f2bf(x1 * cs.x - x2 * cs.y);
  QKV[base + 64] = f2bf(x2 * cs.x + x1 * cs.y);
}

// ---- 128xBN double-buffered bf16 GEMM, BK=64, 2 blocks/CU (R20-proven) ----
template <int BN, int OUT_BF16>
__global__ __launch_bounds__(512, 4) void gemm_2cu(const u16* __restrict__ A,
                                                   const u16* __restrict__ Bt,
                                                   void* __restrict__ C,
                                                   int M, int N, int K) {
  constexpr int NF = BN / 64;
  constexpr int WCOL = BN / 4;
  constexpr int LB = BN / 64;
  __shared__ alignas(16) u16 As[2][128 * 64];
  __shared__ alignas(16) u16 Bs[2][BN * 64];
  const int tid = threadIdx.x;
  const int lane = tid & 63, wid = tid >> 6;
  const int l15 = lane & 15, lg = lane >> 4;
  const int wm = wid >> 2, wn = wid & 3;
  const int wvb = tid & ~63;

  const int gy = gridDim.y;
  const int id0 = blockIdx.y * gridDim.x + blockIdx.x;
  const int xcd = id0 & 7;
  const int l = id0 >> 3;
  const int m0 = (l % gy) * 128;
  const int n0 = (xcd * (gridDim.x >> 3) + l / gy) * BN;

  f32x4 acc[4][NF];
#pragma unroll
  for (int i = 0; i < 4; ++i)
#pragma unroll
    for (int j = 0; j < NF; ++j) {
      f32x4 zz = {0.f, 0.f, 0.f, 0.f};
      acc[i][j] = zz;
    }

#define STAGE(s_, b_)                                                           \
  do {                                                                          \
    _Pragma("unroll")                                                           \
    for (int p = 0; p < 2; ++p) {                                               \
      const int slot = p * 512 + tid;                                           \
      const int row = slot >> 3, ch = slot & 7;                                 \
      const int col = (ch ^ (row & 7)) * 8;                                     \
      GLD16(A + (size_t)(m0 + row) * K + (s_) * 64 + col,                       \
            &As[b_][(p * 512 + wvb) * 8]);                                      \
    }                                                                           \
    _Pragma("unroll")                                                           \
    for (int p = 0; p < LB; ++p) {                                              \
      const int slot = p * 512 + tid;                                           \
      const int row = slot >> 3, ch = slot & 7;                                 \
      const int col = (ch ^ (row & 7)) * 8;                                     \
      GLD16(Bt + (size_t)(n0 + row) * K + (s_) * 64 + col,                      \
            &Bs[b_][(p * 512 + wvb) * 8]);                                      \
    }                                                                           \
  } while (0)

  STAGE(0, 0);
  __syncthreads();
  int cur = 0;

  const int nt = K >> 6;
  for (int t = 0; t < nt; ++t) {
    if (t + 1 < nt) STAGE(t + 1, cur ^ 1);
#pragma unroll
    for (int g = 0; g < 2; ++g) {
      bf16x8 af[4], bfr[NF];
#pragma unroll
      for (int i = 0; i < 4; ++i) {
        const int row = wm * 64 + i * 16 + l15;
        const int ch = (g * 4 + lg) ^ (row & 7);
        af[i] = *reinterpret_cast<const bf16x8*>(&As[cur][row * 64 + ch * 8]);
      }
#pragma unroll
      for (int j = 0; j < NF; ++j) {
        const int row = wn * WCOL + j * 16 + l15;
        const int ch = (g * 4 + lg) ^ (row & 7);
        bfr[j] = *reinterpret_cast<const bf16x8*>(&Bs[cur][row * 64 + ch * 8]);
      }
      __builtin_amdgcn_s_setprio(1);
#pragma unroll
      for (int i = 0; i < 4; ++i)
#pragma unroll
        for (int j = 0; j < NF; ++j)
          acc[i][j] = __builtin_amdgcn_mfma_f32_16x16x32_bf16(af[i], bfr[j], acc[i][j], 0, 0, 0);
      __builtin_amdgcn_s_setprio(0);
    }
    __syncthreads();
    cur ^= 1;
  }
#undef STAGE

#pragma unroll
  for (int i = 0; i < 4; ++i)
#pragma unroll
    for (int j = 0; j < NF; ++j)
#pragma unroll
      for (int r = 0; r < 4; ++r) {
        const int row = m0 + wm * 64 + i * 16 + lg * 4 + r;
        const int col = n0 + wn * WCOL + j * 16 + l15;
        const float v = acc[i][j][r];
        if (OUT_BF16) ((u16*)C)[(size_t)row * N + col] = f2bf(v);
        else          ((float*)C)[(size_t)row * N + col] = v;
      }
}

// ---------------- GQA causal flash attention ----------------
// 512 single-q-tile blocks, 2 CO-RESIDENT blocks/CU (LDS 74 KB x2 = 148 <= 160,
// VGPR capped via launch_bounds(512,4)). Work pairing: id<256 -> heavy
// (qb = 15-(id&7)); id>=256 -> light (qb = id&7). Round-robin dispatch puts id
// and id+256 on the same CU -> every CU gets exactly 36 tiles in 2 blocks whose
// stage/softmax/drain phases overlap (m114 mechanism).
__global__ __launch_bounds__(512, 4) void attn_kernel(const u16* __restrict__ Q,
                                                      const u16* __restrict__ K,
                                                      const u16* __restrict__ Vt,
                                                      u16* __restrict__ O,
                                                      const int* __restrict__ pos_ptr) {
  const int pos = *pos_ptr;
  const int id = (int)blockIdx.x;
  const int hq = id & 255;
  const int h = hq >> 3;
  const int qb = (id < 256) ? (15 - (hq & 7)) : (hq & 7);
  const int hkv = h >> 2;
  const int tid = threadIdx.x;
  const int w = tid >> 6, lane = tid & 63;
  const int l15 = lane & 15, lg = lane >> 4;

  __shared__ alignas(16) u16 Ks[2][64 * 128];  // K tile [64][128], swizzled
  __shared__ alignas(16) u16 Vs[2][128 * 64];  // V^T tile [128][64], swizzled
  __shared__ alignas(16) u16 Pl[8][16][40];    // per-wave P staging (32 + pad)

  const u16* Kh = K + hkv * 128;                 // row stride 6144
  const u16* Vh = Vt + (size_t)hkv * 128 * 2048; // row stride 2048

  const float C = 0.12752961957823275f;  // (1/sqrt(128)) * log2(e)
  const float THR = 62.0f;               // raw defer-max threshold
  const int wvb = tid & ~63;

#define STAGE_TILE(st_, b_)                                                        \
  do {                                                                             \
    const int s0_ = (st_) * 64;                                                    \
    _Pragma("unroll")                                                              \
    for (int p = 0; p < 2; ++p) {                                                  \
      const int idx = p * 512 + tid;                                               \
      const int kr = idx >> 4, kc = (idx & 15) ^ (kr & 7);                         \
      GLD16(Kh + (size_t)(s0_ + kr) * 6144 + kc * 8, &Ks[b_][(p * 512 + wvb) * 8]);\
      const int vr = idx >> 3, vc = (idx & 7) ^ (vr & 7);                          \
      GLD16(Vh + (size_t)vr * 2048 + s0_ + vc * 8, &Vs[b_][(p * 512 + wvb) * 8]);  \
    }                                                                              \
  } while (0)

  const int qt0 = qb * 128;
  const int nst = 2 * qb + 2;
  const int frag_base = qt0 + w * 16;

  bf16x8 qa[4];
#pragma unroll
  for (int kk = 0; kk < 4; ++kk)
    qa[kk] = *reinterpret_cast<const bf16x8*>(
        Q + (size_t)(frag_base + l15) * 6144 + h * 128 + kk * 32 + lg * 8);

  f32x4 acc[8];
#pragma unroll
  for (int i = 0; i < 8; ++i) { f32x4 z = {0.f, 0.f, 0.f, 0.f}; acc[i] = z; }
  float mrun[4], lpart[4];
#pragma unroll
  for (int r = 0; r < 4; ++r) {
    mrun[r] = (pos > 0) ? 0.0f : -INFINITY;  // zero-key prefix logit = 0 (raw)
    lpart[r] = 0.0f;
  }

  STAGE_TILE(0, 0);
  __syncthreads();
  int cur = 0;

  for (int st = 0; st < nst; ++st) {
    if (st + 1 < nst) STAGE_TILE(st + 1, cur ^ 1);
    const int s0 = st * 64;

    // ---- QK^T (raw logits) ----
    float pv[4][4];
    __builtin_amdgcn_s_setprio(1);
#pragma unroll
    for (int sub = 0; sub < 4; ++sub) {
      f32x4 s4 = {0.f, 0.f, 0.f, 0.f};
      const int row = sub * 16 + l15;
#pragma unroll
      for (int kk = 0; kk < 4; ++kk) {
        const int chunk = (kk * 4 + lg) ^ (row & 7);
        bf16x8 kf = *reinterpret_cast<const bf16x8*>(&Ks[cur][row * 128 + chunk * 8]);
        s4 = __builtin_amdgcn_mfma_f32_16x16x32_bf16(qa[kk], kf, s4, 0, 0, 0);
      }
#pragma unroll
      for (int r = 0; r < 4; ++r) pv[sub][r] = s4[r];
    }
    __builtin_amdgcn_s_setprio(0);

    // ---- causal mask (diagonal tiles only) ----
    if (s0 + 64 > frag_base) {
#pragma unroll
      for (int r = 0; r < 4; ++r) {
        const int qrow = frag_base + lg * 4 + r;
#pragma unroll
        for (int sub = 0; sub < 4; ++sub) {
          const int scol = s0 + sub * 16 + l15;
          pv[sub][r] = (scol <= qrow) ? pv[sub][r] : -INFINITY;
        }
      }
    }

    // ---- defer-max (folded; recompute row-max only on rare rescale) ----
    float dml = -INFINITY;
#pragma unroll
    for (int r = 0; r < 4; ++r)
      dml = fmaxf(dml, fmaxf(fmaxf(pv[0][r], pv[1][r]),
                             fmaxf(pv[2][r], pv[3][r])) - mrun[r]);
    if (!__all(dml <= THR)) {
      float sfr[4];
#pragma unroll
      for (int r = 0; r < 4; ++r) {
        float mx = fmaxf(fmaxf(pv[0][r], pv[1][r]), fmaxf(pv[2][r], pv[3][r]));
#pragma unroll
        for (int off = 1; off < 16; off <<= 1) mx = fmaxf(mx, __shfl_xor(mx, off));
        const float mnew = fmaxf(mrun[r], mx);
        sfr[r] = exp2f((mrun[r] - mnew) * C);
        mrun[r] = mnew;
        lpart[r] *= sfr[r];
      }
#pragma unroll
      for (int dc = 0; dc < 8; ++dc)
#pragma unroll
        for (int r = 0; r < 4; ++r) acc[dc][r] *= sfr[r];
    }

    // ---- two 32-wide halves: exp + P-write (2 subs) then 8 PV MFMA ----
#pragma unroll
    for (int half = 0; half < 2; ++half) {
#pragma unroll
      for (int r = 0; r < 4; ++r) {
        const float nmC = -mrun[r] * C;
        float ps = 0.0f;
#pragma unroll
        for (int s2 = 0; s2 < 2; ++s2) {
          const int sub = half * 2 + s2;
          const float p = exp2f(fmaf(pv[sub][r], C, nmC));
          pv[sub][r] = p;
          ps += p;
        }
        lpart[r] += ps;
      }
#pragma unroll
      for (int s2 = 0; s2 < 2; ++s2)
#pragma unroll
        for (int r = 0; r < 4; ++r)
          Pl[w][lg * 4 + r][s2 * 16 + l15] = f2bf(pv[half * 2 + s2][r]);

      bf16x8 pf = *reinterpret_cast<const bf16x8*>(&Pl[w][l15][lg * 8]);
      __builtin_amdgcn_s_setprio(1);
#pragma unroll
      for (int dc = 0; dc < 8; ++dc) {
        const int row = dc * 16 + l15;
        const int chunk = (half * 4 + lg) ^ (row & 7);
        bf16x8 vf = *reinterpret_cast<const bf16x8*>(&Vs[cur][row * 64 + chunk * 8]);
        acc[dc] = __builtin_amdgcn_mfma_f32_16x16x32_bf16(pf, vf, acc[dc], 0, 0, 0);
      }
      __builtin_amdgcn_s_setprio(0);
    }

    __syncthreads();
    cur ^= 1;
  }

  // ---- epilogue ----
#pragma unroll
  for (int r = 0; r < 4; ++r) {
    float l = lpart[r];
#pragma unroll
    for (int off = 1; off < 16; off <<= 1) l += __shfl_xor(l, off);
    if (pos > 0) l += (float)pos * exp2f(-mrun[r] * C);
    const float linv = 1.0f / l;
    const int qrow = frag_base + lg * 4 + r;
#pragma unroll
    for (int dc = 0; dc < 8; ++dc)
      O[(size_t)qrow * 4096 + h * 128 + dc * 16 + l15] = f2bf(acc[dc][r] * linv);
  }
#undef STAGE_TILE
}

extern "C" void kernel_launch(void* const* d_in, const int* in_sizes, int n_in,
                              void* d_out, int out_size, void* d_ws, size_t ws_size,
                              hipStream_t stream) {
  const float* hs = (const float*)d_in[0];
  const float* Wq = (const float*)d_in[1];
  const float* Wk = (const float*)d_in[2];
  const float* Wv = (const float*)d_in[3];
  const float* Wo = (const float*)d_in[4];
  const int* pos  = (const int*)d_in[5];

  char* ws = (char*)d_ws;
  // layout (88 MB total):
  u16* hs_bf = (u16*)(ws + 0);            // [2048][4096] bf16 (16 MB)
  u16* WT    = (u16*)(ws + 16777216ULL);  // [6144][4096] bf16 (48 MB): Wq|Wk|Wv rows
  u16* QKVb  = (u16*)(ws + 67108864ULL);  // [2048][6144] bf16 (24 MB)
  // aliases of dead regions:
  u16* attnO = hs_bf;                          // [2048][4096], hs_bf dead post-QKV
  u16* WoT   = WT;                             // [4096][4096], WqT rows dead
  u16* Vtg   = (u16*)(ws + 50331648ULL);       // [8][128][2048] (4 MB), WkT rows dead
  float2* tabF = (float2*)(ws + 54525952ULL);  // [2048][64] (1 MB), WvT rows dead

  f32_to_bf16<<<8192, 256, 0, stream>>>(hs, hs_bf, 2097152);
  transpose_qkv_w<<<dim3(192, 128), 256, 0, stream>>>(Wq, Wk, Wv, WT);

  // fused QKV projection, BM=128/BN=192: 512 blocks = 2 blocks/CU
  gemm_2cu<192, 1><<<dim3(32, 16), 512, 0, stream>>>(hs_bf, WT, QKVb, 2048, 6144, 4096);

  // Wo transpose AFTER QKV GEMM (WoT overwrites dead WqT rows)
  transpose_convert<<<dim3(128, 128), 256, 0, stream>>>(Wo, WoT, 4096, 4096);

  rope_table<<<512, 256, 0, stream>>>(tabF, pos);
  rope_apply_qk<<<20480, 256, 0, stream>>>(QKVb, tabF);

  // V cols -> Vt[hkv][d][t]
  transpose_v<<<dim3(64, 4, 8), 256, 0, stream>>>(QKVb + 5120, Vtg);

  // attn: 512 balanced single-q-tile blocks, 2 co-resident blocks/CU
  attn_kernel<<<dim3(512), 512, 0, stream>>>(QKVb, QKVb + 4096, Vtg, attnO, pos);

  // output projection, BM=128/BN=128: 512 blocks = 2 blocks/CU, direct fp32 out
  gemm_2cu<128, 0><<<dim3(32, 16), 512, 0, stream>>>(attnO, WoT, d_out, 2048, 4096, 4096);
}